// Round 10
// baseline (1888.790 us; speedup 1.0000x reference)
//
#include <hip/hip_runtime.h>

#define N_NODES 200000
#define N_EDGES 800000
#define N_RULES 50000
#define NLAYERS 24
#define SCAN_NB 196        // ceil(200000/1024)
#define RP_STRIDE 200064   // ints per rp array (padded)

typedef short bf16x8 __attribute__((ext_vector_type(8)));
typedef float floatx4 __attribute__((ext_vector_type(4)));

__device__ __forceinline__ unsigned short f2bf(float f) {
  unsigned int b = __float_as_uint(f);
  b += 0x7FFFu + ((b >> 16) & 1u);          // round-to-nearest-even
  return (unsigned short)(b >> 16);
}
__device__ __forceinline__ float bf2f(unsigned short u) {
  return __uint_as_float(((unsigned int)u) << 16);
}

// ---------------- CSR build (unpadded) ----------------

__global__ void k_hist(const int* __restrict__ src, const int* __restrict__ tgt,
                       int* __restrict__ deg_out, int* __restrict__ deg_back) {
  int e = blockIdx.x * 256 + threadIdx.x;   // E = 3125*256 exact
  atomicAdd(&deg_out[tgt[e]], 1);
  atomicAdd(&deg_back[src[e]], 1);
}

__global__ void k_scanA(const int* __restrict__ deg, int* __restrict__ part) {
  int y = blockIdx.y;
  const int* d = deg + y * N_NODES;
  __shared__ int sh[256];
  int t = threadIdx.x;
  int base = blockIdx.x * 1024 + t * 4;
  int s = 0;
  #pragma unroll
  for (int k = 0; k < 4; ++k) { int i = base + k; if (i < N_NODES) s += d[i]; }
  sh[t] = s; __syncthreads();
  for (int off = 128; off > 0; off >>= 1) { if (t < off) sh[t] += sh[t + off]; __syncthreads(); }
  if (t == 0) part[y * SCAN_NB + blockIdx.x] = sh[0];
}

__global__ void k_scanB(int* __restrict__ part, int* __restrict__ rp) {
  int y = blockIdx.y;
  __shared__ int buf[256];
  int t = threadIdx.x;
  int v = (t < SCAN_NB) ? part[y * SCAN_NB + t] : 0;
  buf[t] = v; __syncthreads();
  for (int off = 1; off < 256; off <<= 1) {
    int x = (t >= off) ? buf[t - off] : 0;
    __syncthreads();
    buf[t] += x;
    __syncthreads();
  }
  if (t < SCAN_NB) part[y * SCAN_NB + t] = buf[t] - v;   // exclusive
  if (t == 0) rp[y * RP_STRIDE + N_NODES] = N_EDGES;
}

__global__ void k_scanC(const int* __restrict__ deg, const int* __restrict__ part,
                        int* __restrict__ rp) {
  int y = blockIdx.y;
  const int* d = deg + y * N_NODES;
  int* r = rp + y * RP_STRIDE;
  __shared__ int buf[256];
  int t = threadIdx.x;
  int base = blockIdx.x * 1024 + t * 4;
  int dv[4]; int s = 0;
  #pragma unroll
  for (int k = 0; k < 4; ++k) { int i = base + k; dv[k] = (i < N_NODES) ? d[i] : 0; s += dv[k]; }
  buf[t] = s; __syncthreads();
  int sv = s;
  for (int off = 1; off < 256; off <<= 1) {
    int x = (t >= off) ? buf[t - off] : 0;
    __syncthreads();
    buf[t] += x;
    __syncthreads();
  }
  int e = part[y * SCAN_NB + blockIdx.x] + buf[t] - sv;
  #pragma unroll
  for (int k = 0; k < 4; ++k) { int i = base + k; if (i < N_NODES) r[i] = e; e += dv[k]; }
}

__global__ void k_fill(const int* __restrict__ src, const int* __restrict__ tgt,
                       const int* __restrict__ rp_out, const int* __restrict__ rp_back,
                       int* __restrict__ cur_out, int* __restrict__ cur_back,
                       int* __restrict__ ci_out, int* __restrict__ ci_back) {
  int e = blockIdx.x * 256 + threadIdx.x;
  int s = src[e], t = tgt[e];
  int p = rp_out[t] + atomicAdd(&cur_out[t], 1);
  ci_out[p] = s;
  int q = rp_back[s] + atomicAdd(&cur_back[s], 1);
  ci_back[q] = t;
}

// ---------------- BN-folded weight prep (bf16 MFMA A-fragments) ----------------
__global__ void k_prep(const float* __restrict__ W, const float* __restrict__ b,
                       const float* __restrict__ gamma, const float* __restrict__ beta,
                       const float* __restrict__ rmean, const float* __restrict__ rvar,
                       unsigned short* __restrict__ WpF, float* __restrict__ bp) {
  int d = blockIdx.x, l = blockIdx.y, lane = threadIdx.x;
  int ld = l * 2 + d;
  __shared__ float s_s[64], t_s[64];
  float s = gamma[ld * 64 + lane] * rsqrtf(rvar[ld * 64 + lane] + 1e-5f);
  s_s[lane] = s;
  t_s[lane] = beta[ld * 64 + lane] - rmean[ld * 64 + lane] * s;
  __syncthreads();
  float bias = b[ld * 64 + lane];
  for (int j = 0; j < 64; ++j) bias += W[(ld * 64 + lane) * 64 + j] * t_s[j];
  bp[ld * 64 + lane] = bias;
  #pragma unroll
  for (int f = 0; f < 8; ++f) {
    int ct = f >> 1, kh = f & 1;
    int row = ct * 16 + (lane & 15);
    #pragma unroll
    for (int jj = 0; jj < 8; ++jj) {
      int k = kh * 32 + (lane >> 4) * 8 + jj;
      float val = W[(ld * 64 + row) * 64 + k] * s_s[k];
      WpF[(ld * 8 + f) * 512 + lane * 8 + jj] = f2bf(val);
    }
  }
}

// ---------------- Wh prep: split bf16 hi/lo MFMA A-fragments ----------------
__global__ void k_prep2(const float* __restrict__ Wh,
                        unsigned short* __restrict__ WhFhi,
                        unsigned short* __restrict__ WhFlo) {
  int jt = blockIdx.x, lane = threadIdx.x;
  #pragma unroll
  for (int kh = 0; kh < 2; ++kh) {
    #pragma unroll
    for (int jj = 0; jj < 8; ++jj) {
      int j = jt * 16 + (lane & 15);
      int k = kh * 32 + (lane >> 4) * 8 + jj;
      float wv = Wh[j * 64 + k];
      unsigned short hi = f2bf(wv);
      WhFhi[(jt * 2 + kh) * 512 + lane * 8 + jj] = hi;
      WhFlo[(jt * 2 + kh) * 512 + lane * 8 + jj] = f2bf(wv - bf2f(hi));
    }
  }
}

// ---------------- embedding gather (bf16 hi/lo master) ----------------
__global__ void k_embed(const int* __restrict__ nodes, const float* __restrict__ emb,
                        unsigned short* __restrict__ hi_a,
                        unsigned short* __restrict__ lo) {
  int gid = blockIdx.x * 256 + threadIdx.x;     // N*64 = 50000*256 exact
  int i = gid >> 6, c = gid & 63;
  float v = emb[nodes[i] * 64 + c];
  unsigned short h = f2bf(v);
  hi_a[gid] = h;
  lo[gid] = f2bf(v - bf2f(h));
}

// ---------------- fused layer (32 gathers in flight, hi/lo bf16 master) ----
// gather-mean from hi (both dirs) + BN-folded matvec (MFMA) + in-place residual
// on hi/lo master. 1 wave = 16 consecutive nodes.
__global__ __launch_bounds__(256) void k_layer(
    const unsigned short* __restrict__ hi_in,      // gather source + master hi
    unsigned short* __restrict__ hi_out,
    unsigned short* __restrict__ lo,               // master lo (in-place)
    const int* __restrict__ rp0, const int* __restrict__ ci0,
    const int* __restrict__ rp1, const int* __restrict__ ci1,
    const unsigned short* __restrict__ WfL, const float* __restrict__ bpL) {
  __shared__ __align__(16) unsigned short m_s[4][16 * 72];  // bf16, pitch 72
  __shared__ __align__(16) float y_s[4][16 * 68];           // f32, pitch 68
  __shared__ float bp_s[128];
  __shared__ int rp_s[4][18];
  int tid = threadIdx.x, lane = tid & 63, w = tid >> 6;
  if (tid < 128) bp_s[tid] = bpL[tid];
  __syncthreads();
  int base = (blockIdx.x * 4 + w) * 16;
  int n15 = lane & 15, q = lane >> 4;

  for (int d = 0; d < 2; ++d) {
    const int* rp = d ? rp1 : rp0;
    const int* ci = d ? ci1 : ci0;
    if (lane < 17) rp_s[w][lane] = rp[base + lane];
    int rs = __builtin_amdgcn_readfirstlane(rp_s[w][0]);
    int re = __builtin_amdgcn_readfirstlane(rp_s[w][16]);
    int cur = 0;
    int cstart = rs;
    int cend = __builtin_amdgcn_readfirstlane(rp_s[w][1]);
    float acc = 0.f;
    // prefetch first ci chunk (single coalesced 4B load)
    int cv = (rs + lane < re) ? ci[rs + lane] : 0;
    for (int cb = rs; cb < re; cb += 64) {
      int ce = (cb + 64 < re) ? cb + 64 : re;
      // double-buffer: kick off next chunk's index load before processing this one
      int cv_next = (cb + 64 + lane < re) ? ci[cb + 64 + lane] : 0;
      for (int j0 = cb; j0 < ce; j0 += 32) {
        float v[32];                                   // 32 UNCONDITIONAL gathers in flight
        #pragma unroll
        for (int u = 0; u < 32; ++u) {
          int sn = __builtin_amdgcn_readlane(cv, j0 + u - cb);  // OOB lanes hold 0 -> safe row
          v[u] = bf2f(hi_in[sn * 64 + lane]);
        }
        #pragma unroll
        for (int u = 0; u < 32; ++u) {
          int j = j0 + u;
          if (j < ce) {                                // guard ACCUMULATION only
            while (j >= cend) {                        // flush node `cur`
              int deg = cend - cstart;
              float invc = deg > 0 ? 1.f / (float)deg : 0.f;
              m_s[w][cur * 72 + lane] = f2bf(acc * invc);
              acc = 0.f; cur++;
              cstart = cend;
              cend = __builtin_amdgcn_readfirstlane(rp_s[w][cur + 1]);
            }
            acc += v[u];
          }
        }
      }
      cv = cv_next;
    }
    #pragma unroll 1
    while (cur < 16) {                                 // trailing flush
      int deg = cend - cstart;
      float invc = deg > 0 ? 1.f / (float)deg : 0.f;
      m_s[w][cur * 72 + lane] = f2bf(acc * invc);
      acc = 0.f; cstart = cend; cur++;
      if (cur < 16) cend = __builtin_amdgcn_readfirstlane(rp_s[w][cur + 1]);
    }

    // MFMA: y[64ch x 16node] = W' @ m ; A-frags register-resident from global
    const unsigned short* wf = WfL + d * 4096;
    bf16x8 b0 = *(const bf16x8*)&m_s[w][n15 * 72 + q * 8];
    bf16x8 b1 = *(const bf16x8*)&m_s[w][n15 * 72 + 32 + q * 8];
    #pragma unroll
    for (int ct = 0; ct < 4; ++ct) {
      floatx4 d4 = {0.f, 0.f, 0.f, 0.f};
      bf16x8 a0 = *(const bf16x8*)(wf + (ct * 2 + 0) * 512 + lane * 8);
      bf16x8 a1 = *(const bf16x8*)(wf + (ct * 2 + 1) * 512 + lane * 8);
      d4 = __builtin_amdgcn_mfma_f32_16x16x32_bf16(a0, b0, d4, 0, 0, 0);
      d4 = __builtin_amdgcn_mfma_f32_16x16x32_bf16(a1, b1, d4, 0, 0, 0);
      // D: col = lane&15 = node, row = ct*16 + q*4 + i = channel
      floatx4 yv;
      #pragma unroll
      for (int i = 0; i < 4; ++i)
        yv[i] = fmaxf(d4[i] + bp_s[d * 64 + ct * 16 + q * 4 + i], 0.f);
      float* yp = &y_s[w][n15 * 68 + ct * 16 + q * 4];
      if (d == 0) {
        *(floatx4*)yp = yv;
      } else {
        floatx4 o = *(const floatx4*)yp;
        o += yv;
        *(floatx4*)yp = o;
      }
    }
  }

  // epilogue: row-major coalesced; residual on hi/lo, re-split, store
  #pragma unroll
  for (int r = 0; r < 16; ++r) {
    int gi = (base + r) * 64 + lane;
    float xv = bf2f(hi_in[gi]) + bf2f(lo[gi]) + y_s[w][r * 68 + lane];
    unsigned short h = f2bf(xv);
    hi_out[gi] = h;
    lo[gi] = f2bf(xv - bf2f(h));   // in-place: only this block touches these rows
  }
}

// ---------------- readout (MFMA; hi/lo split comes free from master format) ----
__global__ __launch_bounds__(256) void k_final(
    const unsigned short* __restrict__ hi, const unsigned short* __restrict__ lo,
    const int* __restrict__ rules,
    const unsigned short* __restrict__ WhFhi, const unsigned short* __restrict__ WhFlo,
    const float* __restrict__ bh, const float* __restrict__ Wo,
    float* __restrict__ out) {
  __shared__ __align__(16) float bh_s[1024], wo_s[1024];
  int tid = threadIdx.x, lane = tid & 63, w = tid >> 6;
  ((floatx4*)bh_s)[tid] = ((const floatx4*)bh)[tid];
  ((floatx4*)wo_s)[tid] = ((const floatx4*)Wo)[tid];
  __syncthreads();
  int n15 = lane & 15, q = lane >> 4;
  int rbase = (blockIdx.x * 4 + w) * 16;
  int ru = rbase + n15;
  int nd = rules[ru < N_RULES ? ru : N_RULES - 1];
  bf16x8 b0h = *(const bf16x8*)&hi[nd * 64 + q * 8];
  bf16x8 b1h = *(const bf16x8*)&hi[nd * 64 + 32 + q * 8];
  bf16x8 b0l = *(const bf16x8*)&lo[nd * 64 + q * 8];
  bf16x8 b1l = *(const bf16x8*)&lo[nd * 64 + 32 + q * 8];
  float acc = 0.f;
  #pragma unroll 4
  for (int jt = 0; jt < 64; ++jt) {
    const unsigned short* fh = WhFhi + (jt * 2) * 512 + lane * 8;
    const unsigned short* fl = WhFlo + (jt * 2) * 512 + lane * 8;
    bf16x8 a0h = *(const bf16x8*)fh;
    bf16x8 a1h = *(const bf16x8*)(fh + 512);
    bf16x8 a0l = *(const bf16x8*)fl;
    bf16x8 a1l = *(const bf16x8*)(fl + 512);
    floatx4 d4 = {0.f, 0.f, 0.f, 0.f};
    d4 = __builtin_amdgcn_mfma_f32_16x16x32_bf16(a0h, b0h, d4, 0, 0, 0);
    d4 = __builtin_amdgcn_mfma_f32_16x16x32_bf16(a1h, b1h, d4, 0, 0, 0);
    d4 = __builtin_amdgcn_mfma_f32_16x16x32_bf16(a0h, b0l, d4, 0, 0, 0);
    d4 = __builtin_amdgcn_mfma_f32_16x16x32_bf16(a1h, b1l, d4, 0, 0, 0);
    d4 = __builtin_amdgcn_mfma_f32_16x16x32_bf16(a0l, b0h, d4, 0, 0, 0);
    d4 = __builtin_amdgcn_mfma_f32_16x16x32_bf16(a1l, b1h, d4, 0, 0, 0);
    floatx4 bh4 = *(const floatx4*)&bh_s[jt * 16 + q * 4];
    floatx4 wo4 = *(const floatx4*)&wo_s[jt * 16 + q * 4];
    #pragma unroll
    for (int i = 0; i < 4; ++i)
      acc += fmaxf(d4[i] + bh4[i], 0.f) * wo4[i];
  }
  acc += __shfl_down(acc, 32);     // fold q2,q3 into q0,q1
  acc += __shfl_down(acc, 16);     // fold q1 into q0
  if (lane < 16 && rbase + lane < N_RULES) out[rbase + lane] = acc;
}

// ---------------- launch ----------------
extern "C" void kernel_launch(void* const* d_in, const int* in_sizes, int n_in,
                              void* d_out, int out_size, void* d_ws, size_t ws_size,
                              hipStream_t stream) {
  const int* nodes = (const int*)d_in[0];
  const int* sources = (const int*)d_in[1];
  const int* targets = (const int*)d_in[2];
  const int* rules = (const int*)d_in[3];
  const float* emb = (const float*)d_in[4];
  const float* W = (const float*)d_in[5];
  const float* b = (const float*)d_in[6];
  const float* gamma = (const float*)d_in[7];
  const float* beta = (const float*)d_in[8];
  const float* rmean = (const float*)d_in[9];
  const float* rvar = (const float*)d_in[10];
  const float* Wh = (const float*)d_in[11];
  const float* bh = (const float*)d_in[12];
  const float* Wo = (const float*)d_in[13];
  float* out = (float*)d_out;

  if (ws_size < 89000000u) return;  // need ~88.7 MB scratch

  char* ws = (char*)d_ws;
  unsigned short* hi_a = (unsigned short*)(ws + 0);          // 25.6 MB
  unsigned short* hi_b = (unsigned short*)(ws + 25600000);   // 25.6 MB
  unsigned short* lo   = (unsigned short*)(ws + 51200000);   // 25.6 MB
  int* deg_out  = (int*)(ws + 76800000);                     // 800 KB
  int* deg_back = (int*)(ws + 77600000);                     // 800 KB
  int* cur_out  = (int*)(ws + 78400000);                     // 800 KB
  int* cur_back = (int*)(ws + 79200000);                     // 800 KB
  int* rp_out   = (int*)(ws + 80000000);                     // RP_STRIDE ints
  int* rp_back  = (int*)(ws + 80800256);
  int* ci_out   = (int*)(ws + 81600512);                     // 3.2 MB
  int* ci_back  = (int*)(ws + 84800512);                     // 3.2 MB
  int* part     = (int*)(ws + 88000512);                     // 1568 B
  unsigned short* WpF   = (unsigned short*)(ws + 88002080);  // 384 KB (16B aligned)
  float* bp             = (float*)(ws + 88395296);           // 12 KB
  unsigned short* WhFhi = (unsigned short*)(ws + 88407584);  // 128 KB
  unsigned short* WhFlo = (unsigned short*)(ws + 88538656);  // 128 KB -> ends 88,669,728

  // zero deg_out/deg_back/cur_out/cur_back (contiguous 3.2 MB)
  (void)hipMemsetAsync(deg_out, 0, 3200000u, stream);

  k_hist<<<3125, 256, 0, stream>>>(sources, targets, deg_out, deg_back);
  k_scanA<<<dim3(SCAN_NB, 2), 256, 0, stream>>>(deg_out, part);
  k_scanB<<<dim3(1, 2), 256, 0, stream>>>(part, rp_out);
  k_scanC<<<dim3(SCAN_NB, 2), 256, 0, stream>>>(deg_out, part, rp_out);
  k_fill<<<3125, 256, 0, stream>>>(sources, targets, rp_out, rp_back,
                                   cur_out, cur_back, ci_out, ci_back);
  k_prep<<<dim3(2, NLAYERS), 64, 0, stream>>>(W, b, gamma, beta, rmean, rvar, WpF, bp);
  k_prep2<<<64, 64, 0, stream>>>(Wh, WhFhi, WhFlo);
  k_embed<<<50000, 256, 0, stream>>>(nodes, emb, hi_a, lo);

  const unsigned short* hin = hi_a;
  unsigned short* hout = hi_b;
  for (int l = 0; l < NLAYERS; ++l) {
    k_layer<<<3125, 256, 0, stream>>>(hin, hout, lo,
                                      rp_out, ci_out, rp_back, ci_back,
                                      WpF + (size_t)l * 8192, bp + (size_t)l * 128);
    const unsigned short* tmp = hin; hin = hout; hout = (unsigned short*)tmp;
  }
  k_final<<<782, 256, 0, stream>>>(hin, lo, rules, WhFhi, WhFlo, bh, Wo, out);
}

// Round 11
// 1770.106 us; speedup vs baseline: 1.0670x; 1.0670x over previous
//
#include <hip/hip_runtime.h>

#define N_NODES 200000
#define N_EDGES 800000
#define N_RULES 50000
#define NLAYERS 24
#define SCAN_NB 196        // ceil(200000/1024)
#define RP_STRIDE 200064   // ints per rp array (padded)

typedef short bf16x8 __attribute__((ext_vector_type(8)));
typedef float floatx4 __attribute__((ext_vector_type(4)));

__device__ __forceinline__ unsigned short f2bf(float f) {
  unsigned int b = __float_as_uint(f);
  b += 0x7FFFu + ((b >> 16) & 1u);          // round-to-nearest-even
  return (unsigned short)(b >> 16);
}
__device__ __forceinline__ float bf2f(unsigned short u) {
  return __uint_as_float(((unsigned int)u) << 16);
}

// ---------------- CSR build (unpadded; rank captured in hist) ----------------

__global__ void k_hist(const int* __restrict__ src, const int* __restrict__ tgt,
                       int* __restrict__ deg_out, int* __restrict__ deg_back,
                       int* __restrict__ rank_out, int* __restrict__ rank_back) {
  int e = blockIdx.x * 256 + threadIdx.x;   // E = 3125*256 exact
  rank_out[e]  = atomicAdd(&deg_out[tgt[e]], 1);   // rank = old count
  rank_back[e] = atomicAdd(&deg_back[src[e]], 1);
}

__global__ void k_scanA(const int* __restrict__ deg, int* __restrict__ part) {
  int y = blockIdx.y;
  const int* d = deg + y * N_NODES;
  __shared__ int sh[256];
  int t = threadIdx.x;
  int base = blockIdx.x * 1024 + t * 4;
  int s = 0;
  #pragma unroll
  for (int k = 0; k < 4; ++k) { int i = base + k; if (i < N_NODES) s += d[i]; }
  sh[t] = s; __syncthreads();
  for (int off = 128; off > 0; off >>= 1) { if (t < off) sh[t] += sh[t + off]; __syncthreads(); }
  if (t == 0) part[y * SCAN_NB + blockIdx.x] = sh[0];
}

__global__ void k_scanB(int* __restrict__ part, int* __restrict__ rp) {
  int y = blockIdx.y;
  __shared__ int buf[256];
  int t = threadIdx.x;
  int v = (t < SCAN_NB) ? part[y * SCAN_NB + t] : 0;
  buf[t] = v; __syncthreads();
  for (int off = 1; off < 256; off <<= 1) {
    int x = (t >= off) ? buf[t - off] : 0;
    __syncthreads();
    buf[t] += x;
    __syncthreads();
  }
  if (t < SCAN_NB) part[y * SCAN_NB + t] = buf[t] - v;   // exclusive
  if (t == 0) rp[y * RP_STRIDE + N_NODES] = N_EDGES;
}

__global__ void k_scanC(const int* __restrict__ deg, const int* __restrict__ part,
                        int* __restrict__ rp) {
  int y = blockIdx.y;
  const int* d = deg + y * N_NODES;
  int* r = rp + y * RP_STRIDE;
  __shared__ int buf[256];
  int t = threadIdx.x;
  int base = blockIdx.x * 1024 + t * 4;
  int dv[4]; int s = 0;
  #pragma unroll
  for (int k = 0; k < 4; ++k) { int i = base + k; dv[k] = (i < N_NODES) ? d[i] : 0; s += dv[k]; }
  buf[t] = s; __syncthreads();
  int sv = s;
  for (int off = 1; off < 256; off <<= 1) {
    int x = (t >= off) ? buf[t - off] : 0;
    __syncthreads();
    buf[t] += x;
    __syncthreads();
  }
  int e = part[y * SCAN_NB + blockIdx.x] + buf[t] - sv;
  #pragma unroll
  for (int k = 0; k < 4; ++k) { int i = base + k; if (i < N_NODES) r[i] = e; e += dv[k]; }
}

// atomic-free fill: slot = rp[node] + rank[e]
__global__ void k_fill(const int* __restrict__ src, const int* __restrict__ tgt,
                       const int* __restrict__ rp_out, const int* __restrict__ rp_back,
                       const int* __restrict__ rank_out, const int* __restrict__ rank_back,
                       int* __restrict__ ci_out, int* __restrict__ ci_back) {
  int e = blockIdx.x * 256 + threadIdx.x;
  int s = src[e], t = tgt[e];
  ci_out[rp_out[t] + rank_out[e]] = s;
  ci_back[rp_back[s] + rank_back[e]] = t;
}

// ---------------- BN-folded weight prep (bf16 MFMA A-fragments) ----------------
__global__ void k_prep(const float* __restrict__ W, const float* __restrict__ b,
                       const float* __restrict__ gamma, const float* __restrict__ beta,
                       const float* __restrict__ rmean, const float* __restrict__ rvar,
                       unsigned short* __restrict__ WpF, float* __restrict__ bp) {
  int d = blockIdx.x, l = blockIdx.y, lane = threadIdx.x;
  int ld = l * 2 + d;
  __shared__ float s_s[64], t_s[64];
  float s = gamma[ld * 64 + lane] * rsqrtf(rvar[ld * 64 + lane] + 1e-5f);
  s_s[lane] = s;
  t_s[lane] = beta[ld * 64 + lane] - rmean[ld * 64 + lane] * s;
  __syncthreads();
  float bias = b[ld * 64 + lane];
  for (int j = 0; j < 64; ++j) bias += W[(ld * 64 + lane) * 64 + j] * t_s[j];
  bp[ld * 64 + lane] = bias;
  #pragma unroll
  for (int f = 0; f < 8; ++f) {
    int ct = f >> 1, kh = f & 1;
    int row = ct * 16 + (lane & 15);
    #pragma unroll
    for (int jj = 0; jj < 8; ++jj) {
      int k = kh * 32 + (lane >> 4) * 8 + jj;
      float val = W[(ld * 64 + row) * 64 + k] * s_s[k];
      WpF[(ld * 8 + f) * 512 + lane * 8 + jj] = f2bf(val);
    }
  }
}

// ---------------- Wh prep: split bf16 hi/lo MFMA A-fragments ----------------
__global__ void k_prep2(const float* __restrict__ Wh,
                        unsigned short* __restrict__ WhFhi,
                        unsigned short* __restrict__ WhFlo) {
  int jt = blockIdx.x, lane = threadIdx.x;
  #pragma unroll
  for (int kh = 0; kh < 2; ++kh) {
    #pragma unroll
    for (int jj = 0; jj < 8; ++jj) {
      int j = jt * 16 + (lane & 15);
      int k = kh * 32 + (lane >> 4) * 8 + jj;
      float wv = Wh[j * 64 + k];
      unsigned short hi = f2bf(wv);
      WhFhi[(jt * 2 + kh) * 512 + lane * 8 + jj] = hi;
      WhFlo[(jt * 2 + kh) * 512 + lane * 8 + jj] = f2bf(wv - bf2f(hi));
    }
  }
}

// ---------------- embedding gather (bf16 hi/lo master) ----------------
__global__ void k_embed(const int* __restrict__ nodes, const float* __restrict__ emb,
                        unsigned short* __restrict__ hi_a,
                        unsigned short* __restrict__ lo) {
  int gid = blockIdx.x * 256 + threadIdx.x;     // N*64 = 50000*256 exact
  int i = gid >> 6, c = gid & 63;
  float v = emb[nodes[i] * 64 + c];
  unsigned short h = f2bf(v);
  hi_a[gid] = h;
  lo[gid] = f2bf(v - bf2f(h));
}

// ---------------- fused layer (round-9 structure: 16 gathers in flight) ----
// gather-mean from hi (both dirs) + BN-folded matvec (MFMA) + in-place residual
// on hi/lo master. 1 wave = 16 consecutive nodes.
__global__ __launch_bounds__(256) void k_layer(
    const unsigned short* __restrict__ hi_in,      // gather source + master hi
    unsigned short* __restrict__ hi_out,
    unsigned short* __restrict__ lo,               // master lo (in-place)
    const int* __restrict__ rp0, const int* __restrict__ ci0,
    const int* __restrict__ rp1, const int* __restrict__ ci1,
    const unsigned short* __restrict__ WfL, const float* __restrict__ bpL) {
  __shared__ __align__(16) unsigned short m_s[4][16 * 72];  // bf16, pitch 72
  __shared__ __align__(16) float y_s[4][16 * 68];           // f32, pitch 68
  __shared__ float bp_s[128];
  __shared__ int rp_s[4][18];
  int tid = threadIdx.x, lane = tid & 63, w = tid >> 6;
  if (tid < 128) bp_s[tid] = bpL[tid];
  __syncthreads();
  int base = (blockIdx.x * 4 + w) * 16;
  int n15 = lane & 15, q = lane >> 4;

  for (int d = 0; d < 2; ++d) {
    const int* rp = d ? rp1 : rp0;
    const int* ci = d ? ci1 : ci0;
    if (lane < 17) rp_s[w][lane] = rp[base + lane];
    int rs = __builtin_amdgcn_readfirstlane(rp_s[w][0]);
    int re = __builtin_amdgcn_readfirstlane(rp_s[w][16]);
    int cur = 0;
    int cstart = rs;
    int cend = __builtin_amdgcn_readfirstlane(rp_s[w][1]);
    float acc = 0.f;
    // prefetch first ci chunk (single coalesced 4B load)
    int cv = (rs + lane < re) ? ci[rs + lane] : 0;
    for (int cb = rs; cb < re; cb += 64) {
      int ce = (cb + 64 < re) ? cb + 64 : re;
      // double-buffer: kick off next chunk's index load before processing this one
      int cv_next = (cb + 64 + lane < re) ? ci[cb + 64 + lane] : 0;
      for (int j0 = cb; j0 < ce; j0 += 16) {
        float v[16];                                   // 16 UNCONDITIONAL gathers in flight
        #pragma unroll
        for (int u = 0; u < 16; ++u) {
          int sn = __builtin_amdgcn_readlane(cv, j0 + u - cb);  // OOB lanes hold 0 -> safe row
          v[u] = bf2f(hi_in[sn * 64 + lane]);
        }
        #pragma unroll
        for (int u = 0; u < 16; ++u) {
          int j = j0 + u;
          if (j < ce) {                                // guard ACCUMULATION only
            while (j >= cend) {                        // flush node `cur`
              int deg = cend - cstart;
              float invc = deg > 0 ? 1.f / (float)deg : 0.f;
              m_s[w][cur * 72 + lane] = f2bf(acc * invc);
              acc = 0.f; cur++;
              cstart = cend;
              cend = __builtin_amdgcn_readfirstlane(rp_s[w][cur + 1]);
            }
            acc += v[u];
          }
        }
      }
      cv = cv_next;
    }
    #pragma unroll 1
    while (cur < 16) {                                 // trailing flush
      int deg = cend - cstart;
      float invc = deg > 0 ? 1.f / (float)deg : 0.f;
      m_s[w][cur * 72 + lane] = f2bf(acc * invc);
      acc = 0.f; cstart = cend; cur++;
      if (cur < 16) cend = __builtin_amdgcn_readfirstlane(rp_s[w][cur + 1]);
    }

    // MFMA: y[64ch x 16node] = W' @ m ; A-frags register-resident from global
    const unsigned short* wf = WfL + d * 4096;
    bf16x8 b0 = *(const bf16x8*)&m_s[w][n15 * 72 + q * 8];
    bf16x8 b1 = *(const bf16x8*)&m_s[w][n15 * 72 + 32 + q * 8];
    #pragma unroll
    for (int ct = 0; ct < 4; ++ct) {
      floatx4 d4 = {0.f, 0.f, 0.f, 0.f};
      bf16x8 a0 = *(const bf16x8*)(wf + (ct * 2 + 0) * 512 + lane * 8);
      bf16x8 a1 = *(const bf16x8*)(wf + (ct * 2 + 1) * 512 + lane * 8);
      d4 = __builtin_amdgcn_mfma_f32_16x16x32_bf16(a0, b0, d4, 0, 0, 0);
      d4 = __builtin_amdgcn_mfma_f32_16x16x32_bf16(a1, b1, d4, 0, 0, 0);
      // D: col = lane&15 = node, row = ct*16 + q*4 + i = channel
      floatx4 yv;
      #pragma unroll
      for (int i = 0; i < 4; ++i)
        yv[i] = fmaxf(d4[i] + bp_s[d * 64 + ct * 16 + q * 4 + i], 0.f);
      float* yp = &y_s[w][n15 * 68 + ct * 16 + q * 4];
      if (d == 0) {
        *(floatx4*)yp = yv;
      } else {
        floatx4 o = *(const floatx4*)yp;
        o += yv;
        *(floatx4*)yp = o;
      }
    }
  }

  // epilogue: row-major coalesced; residual on hi/lo, re-split, store
  #pragma unroll
  for (int r = 0; r < 16; ++r) {
    int gi = (base + r) * 64 + lane;
    float xv = bf2f(hi_in[gi]) + bf2f(lo[gi]) + y_s[w][r * 68 + lane];
    unsigned short h = f2bf(xv);
    hi_out[gi] = h;
    lo[gi] = f2bf(xv - bf2f(h));   // in-place: only this block touches these rows
  }
}

// ---------------- readout (MFMA; hi/lo split comes free from master format) ----
__global__ __launch_bounds__(256) void k_final(
    const unsigned short* __restrict__ hi, const unsigned short* __restrict__ lo,
    const int* __restrict__ rules,
    const unsigned short* __restrict__ WhFhi, const unsigned short* __restrict__ WhFlo,
    const float* __restrict__ bh, const float* __restrict__ Wo,
    float* __restrict__ out) {
  __shared__ __align__(16) float bh_s[1024], wo_s[1024];
  int tid = threadIdx.x, lane = tid & 63, w = tid >> 6;
  ((floatx4*)bh_s)[tid] = ((const floatx4*)bh)[tid];
  ((floatx4*)wo_s)[tid] = ((const floatx4*)Wo)[tid];
  __syncthreads();
  int n15 = lane & 15, q = lane >> 4;
  int rbase = (blockIdx.x * 4 + w) * 16;
  int ru = rbase + n15;
  int nd = rules[ru < N_RULES ? ru : N_RULES - 1];
  bf16x8 b0h = *(const bf16x8*)&hi[nd * 64 + q * 8];
  bf16x8 b1h = *(const bf16x8*)&hi[nd * 64 + 32 + q * 8];
  bf16x8 b0l = *(const bf16x8*)&lo[nd * 64 + q * 8];
  bf16x8 b1l = *(const bf16x8*)&lo[nd * 64 + 32 + q * 8];
  float acc = 0.f;
  #pragma unroll 4
  for (int jt = 0; jt < 64; ++jt) {
    const unsigned short* fh = WhFhi + (jt * 2) * 512 + lane * 8;
    const unsigned short* fl = WhFlo + (jt * 2) * 512 + lane * 8;
    bf16x8 a0h = *(const bf16x8*)fh;
    bf16x8 a1h = *(const bf16x8*)(fh + 512);
    bf16x8 a0l = *(const bf16x8*)fl;
    bf16x8 a1l = *(const bf16x8*)(fl + 512);
    floatx4 d4 = {0.f, 0.f, 0.f, 0.f};
    d4 = __builtin_amdgcn_mfma_f32_16x16x32_bf16(a0h, b0h, d4, 0, 0, 0);
    d4 = __builtin_amdgcn_mfma_f32_16x16x32_bf16(a1h, b1h, d4, 0, 0, 0);
    d4 = __builtin_amdgcn_mfma_f32_16x16x32_bf16(a0h, b0l, d4, 0, 0, 0);
    d4 = __builtin_amdgcn_mfma_f32_16x16x32_bf16(a1h, b1l, d4, 0, 0, 0);
    d4 = __builtin_amdgcn_mfma_f32_16x16x32_bf16(a0l, b0h, d4, 0, 0, 0);
    d4 = __builtin_amdgcn_mfma_f32_16x16x32_bf16(a1l, b1h, d4, 0, 0, 0);
    floatx4 bh4 = *(const floatx4*)&bh_s[jt * 16 + q * 4];
    floatx4 wo4 = *(const floatx4*)&wo_s[jt * 16 + q * 4];
    #pragma unroll
    for (int i = 0; i < 4; ++i)
      acc += fmaxf(d4[i] + bh4[i], 0.f) * wo4[i];
  }
  acc += __shfl_down(acc, 32);     // fold q2,q3 into q0,q1
  acc += __shfl_down(acc, 16);     // fold q1 into q0
  if (lane < 16 && rbase + lane < N_RULES) out[rbase + lane] = acc;
}

// ---------------- launch ----------------
extern "C" void kernel_launch(void* const* d_in, const int* in_sizes, int n_in,
                              void* d_out, int out_size, void* d_ws, size_t ws_size,
                              hipStream_t stream) {
  const int* nodes = (const int*)d_in[0];
  const int* sources = (const int*)d_in[1];
  const int* targets = (const int*)d_in[2];
  const int* rules = (const int*)d_in[3];
  const float* emb = (const float*)d_in[4];
  const float* W = (const float*)d_in[5];
  const float* b = (const float*)d_in[6];
  const float* gamma = (const float*)d_in[7];
  const float* beta = (const float*)d_in[8];
  const float* rmean = (const float*)d_in[9];
  const float* rvar = (const float*)d_in[10];
  const float* Wh = (const float*)d_in[11];
  const float* bh = (const float*)d_in[12];
  const float* Wo = (const float*)d_in[13];
  float* out = (float*)d_out;

  if (ws_size < 95100000u) return;  // need ~95.1 MB scratch

  char* ws = (char*)d_ws;
  unsigned short* hi_a = (unsigned short*)(ws + 0);          // 25.6 MB
  unsigned short* hi_b = (unsigned short*)(ws + 25600000);   // 25.6 MB
  unsigned short* lo   = (unsigned short*)(ws + 51200000);   // 25.6 MB
  int* deg_out  = (int*)(ws + 76800000);                     // 800 KB
  int* deg_back = (int*)(ws + 77600000);                     // 800 KB
  int* rank_out = (int*)(ws + 78400000);                     // 3.2 MB
  int* rank_back= (int*)(ws + 81600000);                     // 3.2 MB
  int* rp_out   = (int*)(ws + 84800000);                     // RP_STRIDE ints
  int* rp_back  = (int*)(ws + 85600256);
  int* ci_out   = (int*)(ws + 86400512);                     // 3.2 MB
  int* ci_back  = (int*)(ws + 89600512);                     // 3.2 MB
  int* part     = (int*)(ws + 92800512);                     // 1568 B
  unsigned short* WpF   = (unsigned short*)(ws + 92802080);  // 384 KB (16B aligned)
  float* bp             = (float*)(ws + 93195296);           // 12 KB
  unsigned short* WhFhi = (unsigned short*)(ws + 93207584);  // 128 KB
  unsigned short* WhFlo = (unsigned short*)(ws + 93338656);  // 128 KB -> ends 93,469,728

  // zero deg_out/deg_back (contiguous 1.6 MB)
  (void)hipMemsetAsync(deg_out, 0, 1600000u, stream);

  k_hist<<<3125, 256, 0, stream>>>(sources, targets, deg_out, deg_back,
                                   rank_out, rank_back);
  k_scanA<<<dim3(SCAN_NB, 2), 256, 0, stream>>>(deg_out, part);
  k_scanB<<<dim3(1, 2), 256, 0, stream>>>(part, rp_out);
  k_scanC<<<dim3(SCAN_NB, 2), 256, 0, stream>>>(deg_out, part, rp_out);
  k_fill<<<3125, 256, 0, stream>>>(sources, targets, rp_out, rp_back,
                                   rank_out, rank_back, ci_out, ci_back);
  k_prep<<<dim3(2, NLAYERS), 64, 0, stream>>>(W, b, gamma, beta, rmean, rvar, WpF, bp);
  k_prep2<<<64, 64, 0, stream>>>(Wh, WhFhi, WhFlo);
  k_embed<<<50000, 256, 0, stream>>>(nodes, emb, hi_a, lo);

  const unsigned short* hin = hi_a;
  unsigned short* hout = hi_b;
  for (int l = 0; l < NLAYERS; ++l) {
    k_layer<<<3125, 256, 0, stream>>>(hin, hout, lo,
                                      rp_out, ci_out, rp_back, ci_back,
                                      WpF + (size_t)l * 8192, bp + (size_t)l * 128);
    const unsigned short* tmp = hin; hin = hout; hout = (unsigned short*)tmp;
  }
  k_final<<<782, 256, 0, stream>>>(hin, lo, rules, WhFhi, WhFlo, bh, Wo, out);
}